// Round 13
// baseline (135.195 us; speedup 1.0000x reference)
//
#include <hip/hip_runtime.h>
#include <hip/hip_bf16.h>
#include <math.h>

#define KSCALE 0.08838834764831845f  // 1/sqrt(128)

typedef __bf16 bf16x8 __attribute__((ext_vector_type(8)));
typedef float  f32x4  __attribute__((ext_vector_type(4)));
typedef unsigned short u16x4 __attribute__((ext_vector_type(4)));
typedef unsigned short u16x8 __attribute__((ext_vector_type(8)));

__device__ inline unsigned short f2bf(float f) {
    unsigned int u = __float_as_uint(f);
    unsigned int r = (u + 0x7FFFu + ((u >> 16) & 1u)) >> 16;
    return (unsigned short)r;
}
__device__ __forceinline__ float bf2f(unsigned short u) {
    return __uint_as_float(((unsigned int)u) << 16);
}
__device__ __forceinline__ f32x4 LD4(const float* p) {
    return *reinterpret_cast<const f32x4*>(p);
}
__device__ __forceinline__ f32x4 LD4H(const unsigned short* p) {
    u16x4 t = *reinterpret_cast<const u16x4*>(p);
    f32x4 r = { bf2f(t[0]), bf2f(t[1]), bf2f(t[2]), bf2f(t[3]) };
    return r;
}
__device__ __forceinline__ void ST4(float* p, f32x4 v) {
    *reinterpret_cast<f32x4*>(p) = v;
}

// async global->LDS, 16B per lane; lds dest must be wave-uniform base (+lane*16)
__device__ __forceinline__ void gll16(const unsigned short* g, unsigned short* l) {
    __builtin_amdgcn_global_load_lds(
        (const __attribute__((address_space(1))) unsigned int*)g,
        (__attribute__((address_space(3))) unsigned int*)l,
        16, 0, 0);
}

// ---- K0: prep: x->bf16 (0..511), W transpose 64x64 (512..1535), uf (1536..2047)
__global__ __launch_bounds__(256) void prep_kernel(const float* __restrict__ x,
                                                   unsigned short* __restrict__ xb,
                                                   const float* __restrict__ W,
                                                   unsigned short* __restrict__ Wt,
                                                   const float* __restrict__ Wuf,
                                                   const float* __restrict__ buf,
                                                   const float* __restrict__ m_prev,
                                                   float* __restrict__ fe_ue) {
    int b = blockIdx.x;
    const int tid = threadIdx.x;
    if (b < 512) {
        int t = b * 256 + tid;                    // 131072 float4s
        float4 v = reinterpret_cast<const float4*>(x)[t];
        u16x4 o = { f2bf(v.x), f2bf(v.y), f2bf(v.z), f2bf(v.w) };
        reinterpret_cast<u16x4*>(xb)[t] = o;
    } else if (b < 1536) {
        // transpose+convert: W [1024][4096] f32 -> Wt [4096][1024] bf16, 64x64 tiles
        __shared__ unsigned short tile[64][65];
        int bb = b - 512;                  // 0..1023
        int k0 = (bb & 15) * 64;           // 1024/64
        int n0 = (bb >> 4) * 64;           // 4096/64
        int r16 = tid >> 4, c4 = (tid & 15) * 4;
#pragma unroll
        for (int p = 0; p < 4; ++p) {
            int r = p * 16 + r16;
            float4 v = *reinterpret_cast<const float4*>(&W[(size_t)(k0 + r) * 4096 + n0 + c4]);
            tile[r][c4 + 0] = f2bf(v.x);
            tile[r][c4 + 1] = f2bf(v.y);
            tile[r][c4 + 2] = f2bf(v.z);
            tile[r][c4 + 3] = f2bf(v.w);
        }
        __syncthreads();
        int kc = (tid & 7) * 8, r32 = tid >> 3;
#pragma unroll
        for (int p = 0; p < 2; ++p) {
            int rr = p * 32 + r32;
            u16x8 o;
#pragma unroll
            for (int j = 0; j < 8; ++j) o[j] = tile[kc + j][rr];
            *reinterpret_cast<u16x8*>(&Wt[(size_t)(n0 + rr) * 1024 + k0 + kc]) = o;
        }
    } else {
        // u,f gates (f32 exact). wave w owns output cols 4w..4w+3
        const int n = b - 1536;
        const int lane = tid & 63, w = tid >> 6;
        const float* xr = x + (size_t)n * 1024;
        float4 p = {0.f, 0.f, 0.f, 0.f};
#pragma unroll
        for (int i = 0; i < 16; ++i) {
            int k = lane + i * 64;
            float xv = xr[k];
            float4 wv = *reinterpret_cast<const float4*>(&Wuf[(size_t)k * 16 + 4 * w]);
            p.x += xv * wv.x; p.y += xv * wv.y; p.z += xv * wv.z; p.w += xv * wv.w;
        }
#pragma unroll
        for (int off = 32; off; off >>= 1) {
            p.x += __shfl_down(p.x, off);
            p.y += __shfl_down(p.y, off);
            p.z += __shfl_down(p.z, off);
            p.w += __shfl_down(p.w, off);
        }
        if (lane == 0) {
#pragma unroll
            for (int t = 0; t < 2; ++t) {
                int h = 2 * w + t;
                float u = (t ? p.z : p.x) + buf[4 * w + 2 * t];
                float f = (t ? p.w : p.y) + buf[4 * w + 2 * t + 1];
                float mp = m_prev[h * 512 + n];
                float m = fmaxf(f + mp, u);
                fe_ue[(h * 512 + n) * 2 + 0] = expf(f + mp - m);
                fe_ue[(h * 512 + n) * 2 + 1] = expf(u - m);
            }
        }
    }
}

// ---- K1: split-K=2 GEMM, 128x64 tile, gll16 staging, 2-phase dbuf, bf16 out -
// grid: kh(2) x bm(4) x bn(64) = 512 blocks. Waves 2x2; each wave 64x32 out.
__global__ __launch_bounds__(256) void gemm_qkvo(const unsigned short* __restrict__ A,
                                                 const unsigned short* __restrict__ Bt,
                                                 unsigned short* __restrict__ Cp) {
    __shared__ __align__(16) unsigned short As[2][128 * 64];   // 16 KB each
    __shared__ __align__(16) unsigned short Bs[2][64 * 64];    // 8 KB each
    const int kh = blockIdx.x >> 8;
    const int t8 = blockIdx.x & 255;
    const int bn = t8 & 63;                 // 4096/64 N tiles
    const int bm = t8 >> 6;                 // 512/128 M tiles
    const int m0 = bm * 128, n0 = bn * 64;
    const size_t kb0 = (size_t)kh * 512;
    unsigned short* C = Cp + (size_t)kh * (512 * 4096);
    const int tid = threadIdx.x;
    const int lane = tid & 63, wave = tid >> 6;
    const int wr = wave >> 1, wc = wave & 1;     // wave out: rows wr*64+, cols wc*32+
    f32x4 acc[4][2] = {};

    const int srow = lane >> 3;          // row within 8-row chunk
    const int scol = (lane & 7) * 8;     // k element offset (16B granules)

    // staging: 24 chunks of 8 rows (A: 0..15, B: 16..23); wave w does chunks 6w..6w+5
#define STAGE(bufi, kofs)                                                          \
    {                                                                              \
        _Pragma("unroll")                                                          \
        for (int c = 0; c < 6; ++c) {                                              \
            int chunk = wave * 6 + c;                                              \
            if (chunk < 16) {                                                      \
                int row = chunk * 8 + srow;                                        \
                gll16(A + (size_t)(m0 + row) * 1024 + (kofs) + scol,               \
                      &As[bufi][chunk * 512]);                                     \
            } else {                                                               \
                int row = (chunk - 16) * 8 + srow;                                 \
                gll16(Bt + (size_t)(n0 + row) * 1024 + (kofs) + scol,              \
                      &Bs[bufi][(chunk - 16) * 512]);                              \
            }                                                                      \
        }                                                                          \
    }

    STAGE(0, kb0);
    __syncthreads();

    int cur = 0;
    for (int t = 0; t < 8; ++t) {
        if (t < 7) STAGE(cur ^ 1, kb0 + (t + 1) * 64);
        const unsigned short* as = As[cur];
        const unsigned short* bs = Bs[cur];
        const int row = lane & 15;
        const int kof = (lane >> 4) * 8;
#pragma unroll
        for (int kk = 0; kk < 2; ++kk) {
            int kb = kk * 32 + kof;
            bf16x8 b0 = *reinterpret_cast<const bf16x8*>(&bs[(wc * 32 + row) * 64 + kb]);
            bf16x8 b1 = *reinterpret_cast<const bf16x8*>(&bs[(wc * 32 + 16 + row) * 64 + kb]);
#pragma unroll
            for (int i = 0; i < 4; ++i) {
                bf16x8 ai = *reinterpret_cast<const bf16x8*>(&as[(wr * 64 + i * 16 + row) * 64 + kb]);
                acc[i][0] = __builtin_amdgcn_mfma_f32_16x16x32_bf16(ai, b0, acc[i][0], 0, 0, 0);
                acc[i][1] = __builtin_amdgcn_mfma_f32_16x16x32_bf16(ai, b1, acc[i][1], 0, 0, 0);
            }
        }
        __syncthreads();    // drains gll (vmcnt0 via barrier semantics) + LDS reuse
        cur ^= 1;
    }
#undef STAGE

    // epilogue: acc -> bf16 -> LDS (reuse As[0], 128x64 ushort = 16 KB) -> coalesced
    unsigned short* cs = &As[0][0];
    const int cn = lane & 15, cm = (lane >> 4) * 4;
#pragma unroll
    for (int i = 0; i < 4; ++i)
#pragma unroll
        for (int j = 0; j < 2; ++j) {
            int r0 = wr * 64 + i * 16 + cm;
            int c0 = wc * 32 + j * 16 + cn;
#pragma unroll
            for (int v = 0; v < 4; ++v)
                cs[(r0 + v) * 64 + c0] = f2bf(acc[i][j][v]);
        }
    __syncthreads();
    {
        int row = tid >> 1, half = tid & 1;   // 128 rows x 2 halves of 32 ushort (64 B)
        const u16x8* src = reinterpret_cast<const u16x8*>(&cs[row * 64 + half * 32]);
        u16x8* dst = reinterpret_cast<u16x8*>(&C[(size_t)(m0 + row) * 4096 + n0 + half * 32]);
        dst[0] = src[0];
        dst[1] = src[1];
        dst[2] = src[2];
        dst[3] = src[3];
    }
}

// ---- K2: pure c stream; self-contained preamble from qkvo+bias+fe_ue --------
__global__ __launch_bounds__(256) void stream_c(const float* __restrict__ c_in,
                                                const unsigned short* __restrict__ qkvo,
                                                const float* __restrict__ bias,
                                                const float* __restrict__ fe_ue,
                                                float* __restrict__ c_out) {
    const int hn = blockIdx.x;              // h*512 + n
    const int h = hn >> 9, n = hn & 511;
    const int tid = threadIdx.x;
    __shared__ __align__(16) float uv_s[128], k_s[128];
    const float fe = fe_ue[hn * 2 + 0];
    const float ue = fe_ue[hn * 2 + 1];
    if (tid < 128) {
        const unsigned short* bA = qkvo + (size_t)n * 4096 + h * 512;
        const unsigned short* bB = bA + (size_t)512 * 4096;
        float k = (bf2f(bA[128 + tid]) + bf2f(bB[128 + tid]) + bias[h * 512 + 128 + tid]) * KSCALE;
        float v = bf2f(bA[256 + tid]) + bf2f(bB[256 + tid]) + bias[h * 512 + 256 + tid];
        k_s[tid] = k;
        uv_s[tid] = ue * v;
    }
    __syncthreads();

    const int j4 = (tid & 31) * 4;
    const f32x4 kk = *reinterpret_cast<const f32x4*>(&k_s[j4]);
    const int i0 = tid >> 5;

    const f32x4* cin4 = reinterpret_cast<const f32x4*>(c_in + (size_t)hn * 16384);
    f32x4* cout4 = reinterpret_cast<f32x4*>(c_out + (size_t)hn * 16384);
#pragma unroll
    for (int it = 0; it < 16; ++it) {
        int e4 = tid + it * 256;
        float uvi = uv_s[i0 + it * 8];      // broadcast within 32-lane group
        f32x4 cv = __builtin_nontemporal_load(&cin4[e4]);
        f32x4 ov = fe * cv + uvi * kk;
        __builtin_nontemporal_store(ov, &cout4[e4]);
    }
}

// ---- K3: mid: per-token head math + residual + LayerNorm (independent of K2)
__global__ __launch_bounds__(256) void mid_kernel(const unsigned short* __restrict__ qkvo,
                                                  const float* __restrict__ bias,
                                                  const float* __restrict__ x,
                                                  const float* __restrict__ n_prev,
                                                  const float* __restrict__ fe_ue,
                                                  float* __restrict__ h_out) {
    const int n = blockIdx.x;
    const int tid = threadIdx.x;
    const int g = tid >> 5, l = tid & 31;     // head group, lane-in-group
    __shared__ float hs_s[1024];
    __shared__ float red[8];

    const unsigned short* bA = qkvo + (size_t)n * 4096 + g * 512;
    const unsigned short* bB = bA + (size_t)512 * 4096;
    const float* bs = bias + g * 512;
    const int d4 = l * 4;
    const int hn = g * 512 + n;
    const float fe = fe_ue[hn * 2 + 0];
    const float ue = fe_ue[hn * 2 + 1];

    f32x4 q = LD4H(bA + d4)       + LD4H(bB + d4)       + LD4(bs + d4);
    f32x4 k = (LD4H(bA + 128 + d4) + LD4H(bB + 128 + d4) + LD4(bs + 128 + d4)) * KSCALE;
    f32x4 v = LD4H(bA + 256 + d4) + LD4H(bB + 256 + d4) + LD4(bs + 256 + d4);
    f32x4 o = LD4H(bA + 384 + d4) + LD4H(bB + 384 + d4) + LD4(bs + 384 + d4);
    f32x4 np = LD4(n_prev + (size_t)hn * 128 + d4);
    f32x4 nn = fe * np + ue * k;

    float kq = q[0]*k[0] + q[1]*k[1] + q[2]*k[2] + q[3]*k[3];
    float nq = q[0]*nn[0] + q[1]*nn[1] + q[2]*nn[2] + q[3]*nn[3];
#pragma unroll
    for (int off = 16; off; off >>= 1) {
        kq += __shfl_down(kq, off, 32);
        nq += __shfl_down(nq, off, 32);
    }
    kq = __shfl(kq, 0, 32);
    nq = __shfl(nq, 0, 32);
    const float gs = kq / fmaxf(fabsf(nq), 1.0f);

#pragma unroll
    for (int j = 0; j < 4; ++j)
        hs_s[g * 128 + d4 + j] = v[j] * gs / (1.f + expf(-o[j]));
    __syncthreads();

    // residual + LayerNorm over 1024
    f32x4 hv = *reinterpret_cast<const f32x4*>(&hs_s[tid * 4]);
    f32x4 xv = LD4(x + (size_t)n * 1024 + tid * 4);
    f32x4 s = hv + xv;
    float sum = s[0] + s[1] + s[2] + s[3];
    float sq  = s[0]*s[0] + s[1]*s[1] + s[2]*s[2] + s[3]*s[3];
#pragma unroll
    for (int off = 32; off; off >>= 1) {
        sum += __shfl_down(sum, off);
        sq  += __shfl_down(sq, off);
    }
    const int wv = tid >> 6;
    if ((tid & 63) == 0) { red[wv] = sum; red[4 + wv] = sq; }
    __syncthreads();
    sum = red[0] + red[1] + red[2] + red[3];
    sq  = red[4] + red[5] + red[6] + red[7];
    float mu = sum * (1.f / 1024.f);
    float var = sq * (1.f / 1024.f) - mu * mu;
    float inv = rsqrtf(var + 1e-5f);
    ST4(h_out + (size_t)n * 1024 + tid * 4, (s - mu) * inv);
}

extern "C" void kernel_launch(void* const* d_in, const int* in_sizes, int n_in,
                              void* d_out, int out_size, void* d_ws, size_t ws_size,
                              hipStream_t stream) {
    const float* x      = (const float*)d_in[0];
    const float* c_in   = (const float*)d_in[1];
    const float* m_prev = (const float*)d_in[2];
    const float* n_prev = (const float*)d_in[3];
    const float* Wqkvo  = (const float*)d_in[4];
    const float* bqkvo  = (const float*)d_in[5];
    const float* Wuf    = (const float*)d_in[6];
    const float* buf    = (const float*)d_in[7];
    float* out = (float*)d_out;
    char* ws = (char*)d_ws;

    unsigned short* xb   = (unsigned short*)(ws);                         // 1 MB
    unsigned short* Wt   = (unsigned short*)(ws + (1u << 20));            // 8 MB
    unsigned short* qkvo = (unsigned short*)(ws + 9u * (1u << 20));       // 8 MB (2 bf16 halves)
    float* fe_ue         = (float*)(ws + 17u * (1u << 20));               // 32 KB

    prep_kernel<<<dim3(2048), dim3(256), 0, stream>>>(x, xb, Wqkvo, Wt, Wuf, buf, m_prev, fe_ue);
    gemm_qkvo  <<<dim3(512),  dim3(256), 0, stream>>>(xb, Wt, qkvo);
    stream_c   <<<dim3(4096), dim3(256), 0, stream>>>(c_in, qkvo, bqkvo, fe_ue, out);
    mid_kernel <<<dim3(512),  dim3(256), 0, stream>>>(qkvo, bqkvo, x, n_prev, fe_ue,
                                                      out + 67108864ull);
}

// Round 14
// 132.451 us; speedup vs baseline: 1.0207x; 1.0207x over previous
//
#include <hip/hip_runtime.h>
#include <hip/hip_bf16.h>
#include <math.h>

#define KSCALE 0.08838834764831845f  // 1/sqrt(128)

typedef __bf16 bf16x8 __attribute__((ext_vector_type(8)));
typedef float  f32x4  __attribute__((ext_vector_type(4)));
typedef unsigned short u16x4 __attribute__((ext_vector_type(4)));
typedef unsigned short u16x8 __attribute__((ext_vector_type(8)));

__device__ inline unsigned short f2bf(float f) {
    unsigned int u = __float_as_uint(f);
    unsigned int r = (u + 0x7FFFu + ((u >> 16) & 1u)) >> 16;
    return (unsigned short)r;
}
__device__ __forceinline__ float bf2f(unsigned short u) {
    return __uint_as_float(((unsigned int)u) << 16);
}
__device__ __forceinline__ f32x4 LD4(const float* p) {
    return *reinterpret_cast<const f32x4*>(p);
}
__device__ __forceinline__ f32x4 LD4H(const unsigned short* p) {
    u16x4 t = *reinterpret_cast<const u16x4*>(p);
    f32x4 r = { bf2f(t[0]), bf2f(t[1]), bf2f(t[2]), bf2f(t[3]) };
    return r;
}
__device__ __forceinline__ void ST4(float* p, f32x4 v) {
    *reinterpret_cast<f32x4*>(p) = v;
}

// async global->LDS, 16B per lane; lds dest must be wave-uniform base (+lane*16)
__device__ __forceinline__ void gll16(const unsigned short* g, unsigned short* l) {
    __builtin_amdgcn_global_load_lds(
        (const __attribute__((address_space(1))) unsigned int*)g,
        (__attribute__((address_space(3))) unsigned int*)l,
        16, 0, 0);
}

// ---- K0: prep: x->bf16 (0..511), W transpose 64x64 (512..1535), uf (1536..2047)
__global__ __launch_bounds__(256) void prep_kernel(const float* __restrict__ x,
                                                   unsigned short* __restrict__ xb,
                                                   const float* __restrict__ W,
                                                   unsigned short* __restrict__ Wt,
                                                   const float* __restrict__ Wuf,
                                                   const float* __restrict__ buf,
                                                   const float* __restrict__ m_prev,
                                                   float* __restrict__ fe_ue) {
    int b = blockIdx.x;
    const int tid = threadIdx.x;
    if (b < 512) {
        int t = b * 256 + tid;                    // 131072 float4s
        float4 v = reinterpret_cast<const float4*>(x)[t];
        u16x4 o = { f2bf(v.x), f2bf(v.y), f2bf(v.z), f2bf(v.w) };
        reinterpret_cast<u16x4*>(xb)[t] = o;
    } else if (b < 1536) {
        // transpose+convert: W [1024][4096] f32 -> Wt [4096][1024] bf16, 64x64 tiles
        __shared__ unsigned short tile[64][65];
        int bb = b - 512;                  // 0..1023
        int k0 = (bb & 15) * 64;           // 1024/64
        int n0 = (bb >> 4) * 64;           // 4096/64
        int r16 = tid >> 4, c4 = (tid & 15) * 4;
#pragma unroll
        for (int p = 0; p < 4; ++p) {
            int r = p * 16 + r16;
            float4 v = *reinterpret_cast<const float4*>(&W[(size_t)(k0 + r) * 4096 + n0 + c4]);
            tile[r][c4 + 0] = f2bf(v.x);
            tile[r][c4 + 1] = f2bf(v.y);
            tile[r][c4 + 2] = f2bf(v.z);
            tile[r][c4 + 3] = f2bf(v.w);
        }
        __syncthreads();
        int kc = (tid & 7) * 8, r32 = tid >> 3;
#pragma unroll
        for (int p = 0; p < 2; ++p) {
            int rr = p * 32 + r32;
            u16x8 o;
#pragma unroll
            for (int j = 0; j < 8; ++j) o[j] = tile[kc + j][rr];
            *reinterpret_cast<u16x8*>(&Wt[(size_t)(n0 + rr) * 1024 + k0 + kc]) = o;
        }
    } else {
        // u,f gates (f32 exact). wave w owns output cols 4w..4w+3
        const int n = b - 1536;
        const int lane = tid & 63, w = tid >> 6;
        const float* xr = x + (size_t)n * 1024;
        float4 p = {0.f, 0.f, 0.f, 0.f};
#pragma unroll
        for (int i = 0; i < 16; ++i) {
            int k = lane + i * 64;
            float xv = xr[k];
            float4 wv = *reinterpret_cast<const float4*>(&Wuf[(size_t)k * 16 + 4 * w]);
            p.x += xv * wv.x; p.y += xv * wv.y; p.z += xv * wv.z; p.w += xv * wv.w;
        }
#pragma unroll
        for (int off = 32; off; off >>= 1) {
            p.x += __shfl_down(p.x, off);
            p.y += __shfl_down(p.y, off);
            p.z += __shfl_down(p.z, off);
            p.w += __shfl_down(p.w, off);
        }
        if (lane == 0) {
#pragma unroll
            for (int t = 0; t < 2; ++t) {
                int h = 2 * w + t;
                float u = (t ? p.z : p.x) + buf[4 * w + 2 * t];
                float f = (t ? p.w : p.y) + buf[4 * w + 2 * t + 1];
                float mp = m_prev[h * 512 + n];
                float m = fmaxf(f + mp, u);
                fe_ue[(h * 512 + n) * 2 + 0] = expf(f + mp - m);
                fe_ue[(h * 512 + n) * 2 + 1] = expf(u - m);
            }
        }
    }
}

// ---- K1: split-K=2 GEMM, 64x64 tile (R12 config), gll16 staging, 2-phase dbuf,
//          bf16 partial output via LDS-staged coalesced epilogue --------------
__global__ __launch_bounds__(256) void gemm_qkvo(const unsigned short* __restrict__ A,
                                                 const unsigned short* __restrict__ Bt,
                                                 unsigned short* __restrict__ Cp) {
    __shared__ __align__(16) unsigned short As[2][64 * 64];
    __shared__ __align__(16) unsigned short Bs[2][64 * 64];
    const int kh = blockIdx.x >> 9;
    const int t9 = blockIdx.x & 511;
    const int bn = t9 & 63;                 // 4096/64 N tiles
    const int bm = t9 >> 6;                 // 512/64 M tiles
    const int m0 = bm * 64, n0 = bn * 64;
    const size_t kb0 = (size_t)kh * 512;
    unsigned short* C = Cp + (size_t)kh * (512 * 4096);
    const int tid = threadIdx.x;
    const int lane = tid & 63, wave = tid >> 6;
    const int wr = wave >> 1, wc = wave & 1;     // 2x2 waves, each 32x32 out
    f32x4 acc[2][2] = {};

    const int srow = lane >> 3;          // row within 8-row chunk
    const int scol = (lane & 7) * 8;     // k element offset (16B granules)

#pragma unroll
    for (int c = 0; c < 2; ++c) {
        int chunk = wave * 2 + c;
        int row = chunk * 8 + srow;
        gll16(A + (size_t)(m0 + row) * 1024 + kb0 + scol, &As[0][chunk * 512]);
        gll16(Bt + (size_t)(n0 + row) * 1024 + kb0 + scol, &Bs[0][chunk * 512]);
    }
    __syncthreads();

    int cur = 0;
    for (int t = 0; t < 8; ++t) {
        if (t < 7) {
            size_t k0 = kb0 + (t + 1) * 64;
#pragma unroll
            for (int c = 0; c < 2; ++c) {
                int chunk = wave * 2 + c;
                int row = chunk * 8 + srow;
                gll16(A + (size_t)(m0 + row) * 1024 + k0 + scol, &As[cur ^ 1][chunk * 512]);
                gll16(Bt + (size_t)(n0 + row) * 1024 + k0 + scol, &Bs[cur ^ 1][chunk * 512]);
            }
        }
        const unsigned short* as = As[cur];
        const unsigned short* bs = Bs[cur];
        const int row = lane & 15;
        const int kof = (lane >> 4) * 8;
#pragma unroll
        for (int kk = 0; kk < 2; ++kk) {
            int kb = kk * 32 + kof;
            bf16x8 a0 = *reinterpret_cast<const bf16x8*>(&as[(wr * 32 + row) * 64 + kb]);
            bf16x8 a1 = *reinterpret_cast<const bf16x8*>(&as[(wr * 32 + 16 + row) * 64 + kb]);
            bf16x8 b0 = *reinterpret_cast<const bf16x8*>(&bs[(wc * 32 + row) * 64 + kb]);
            bf16x8 b1 = *reinterpret_cast<const bf16x8*>(&bs[(wc * 32 + 16 + row) * 64 + kb]);
            acc[0][0] = __builtin_amdgcn_mfma_f32_16x16x32_bf16(a0, b0, acc[0][0], 0, 0, 0);
            acc[0][1] = __builtin_amdgcn_mfma_f32_16x16x32_bf16(a0, b1, acc[0][1], 0, 0, 0);
            acc[1][0] = __builtin_amdgcn_mfma_f32_16x16x32_bf16(a1, b0, acc[1][0], 0, 0, 0);
            acc[1][1] = __builtin_amdgcn_mfma_f32_16x16x32_bf16(a1, b1, acc[1][1], 0, 0, 0);
        }
        __syncthreads();
        cur ^= 1;
    }

    // epilogue: acc -> bf16 -> LDS (reuse As, now dead) -> coalesced global
    unsigned short* cs = &As[0][0];          // [64][64] ushort = 8 KB
    const int cn = lane & 15, cm = (lane >> 4) * 4;
#pragma unroll
    for (int i = 0; i < 2; ++i)
#pragma unroll
        for (int j = 0; j < 2; ++j) {
            int r0 = wr * 32 + i * 16 + cm;
            int c0 = wc * 32 + j * 16 + cn;
#pragma unroll
            for (int v = 0; v < 4; ++v)
                cs[(r0 + v) * 64 + c0] = f2bf(acc[i][j][v]);
        }
    __syncthreads();
    {
        int row = tid >> 2, seg = tid & 3;   // 64 rows x 4 segs of 16 ushort
        const u16x8* src = reinterpret_cast<const u16x8*>(&cs[row * 64 + seg * 16]);
        u16x8* dst = reinterpret_cast<u16x8*>(&C[(size_t)(m0 + row) * 4096 + n0 + seg * 16]);
        dst[0] = src[0];
        dst[1] = src[1];
    }
}

// ---- K2: pure c stream; self-contained preamble from qkvo+bias+fe_ue --------
__global__ __launch_bounds__(256) void stream_c(const float* __restrict__ c_in,
                                                const unsigned short* __restrict__ qkvo,
                                                const float* __restrict__ bias,
                                                const float* __restrict__ fe_ue,
                                                float* __restrict__ c_out) {
    const int hn = blockIdx.x;              // h*512 + n
    const int h = hn >> 9, n = hn & 511;
    const int tid = threadIdx.x;
    __shared__ __align__(16) float uv_s[128], k_s[128];
    const float fe = fe_ue[hn * 2 + 0];
    const float ue = fe_ue[hn * 2 + 1];
    if (tid < 128) {
        const unsigned short* bA = qkvo + (size_t)n * 4096 + h * 512;
        const unsigned short* bB = bA + (size_t)512 * 4096;
        float k = (bf2f(bA[128 + tid]) + bf2f(bB[128 + tid]) + bias[h * 512 + 128 + tid]) * KSCALE;
        float v = bf2f(bA[256 + tid]) + bf2f(bB[256 + tid]) + bias[h * 512 + 256 + tid];
        k_s[tid] = k;
        uv_s[tid] = ue * v;
    }
    __syncthreads();

    const int j4 = (tid & 31) * 4;
    const f32x4 kk = *reinterpret_cast<const f32x4*>(&k_s[j4]);
    const int i0 = tid >> 5;

    const f32x4* cin4 = reinterpret_cast<const f32x4*>(c_in + (size_t)hn * 16384);
    f32x4* cout4 = reinterpret_cast<f32x4*>(c_out + (size_t)hn * 16384);
#pragma unroll
    for (int it = 0; it < 16; ++it) {
        int e4 = tid + it * 256;
        float uvi = uv_s[i0 + it * 8];      // broadcast within 32-lane group
        f32x4 cv = __builtin_nontemporal_load(&cin4[e4]);
        f32x4 ov = fe * cv + uvi * kk;
        __builtin_nontemporal_store(ov, &cout4[e4]);
    }
}

// ---- K3: mid: per-token head math + residual + LayerNorm --------------------
__global__ __launch_bounds__(256) void mid_kernel(const unsigned short* __restrict__ qkvo,
                                                  const float* __restrict__ bias,
                                                  const float* __restrict__ x,
                                                  const float* __restrict__ n_prev,
                                                  const float* __restrict__ fe_ue,
                                                  float* __restrict__ h_out) {
    const int n = blockIdx.x;
    const int tid = threadIdx.x;
    const int g = tid >> 5, l = tid & 31;     // head group, lane-in-group
    __shared__ float hs_s[1024];
    __shared__ float red[8];

    const unsigned short* bA = qkvo + (size_t)n * 4096 + g * 512;
    const unsigned short* bB = bA + (size_t)512 * 4096;
    const float* bs = bias + g * 512;
    const int d4 = l * 4;
    const int hn = g * 512 + n;
    const float fe = fe_ue[hn * 2 + 0];
    const float ue = fe_ue[hn * 2 + 1];

    f32x4 q = LD4H(bA + d4)       + LD4H(bB + d4)       + LD4(bs + d4);
    f32x4 k = (LD4H(bA + 128 + d4) + LD4H(bB + 128 + d4) + LD4(bs + 128 + d4)) * KSCALE;
    f32x4 v = LD4H(bA + 256 + d4) + LD4H(bB + 256 + d4) + LD4(bs + 256 + d4);
    f32x4 o = LD4H(bA + 384 + d4) + LD4H(bB + 384 + d4) + LD4(bs + 384 + d4);
    f32x4 np = LD4(n_prev + (size_t)hn * 128 + d4);
    f32x4 nn = fe * np + ue * k;

    float kq = q[0]*k[0] + q[1]*k[1] + q[2]*k[2] + q[3]*k[3];
    float nq = q[0]*nn[0] + q[1]*nn[1] + q[2]*nn[2] + q[3]*nn[3];
#pragma unroll
    for (int off = 16; off; off >>= 1) {
        kq += __shfl_down(kq, off, 32);
        nq += __shfl_down(nq, off, 32);
    }
    kq = __shfl(kq, 0, 32);
    nq = __shfl(nq, 0, 32);
    const float gs = kq / fmaxf(fabsf(nq), 1.0f);

#pragma unroll
    for (int j = 0; j < 4; ++j)
        hs_s[g * 128 + d4 + j] = v[j] * gs / (1.f + expf(-o[j]));
    __syncthreads();

    // residual + LayerNorm over 1024
    f32x4 hv = *reinterpret_cast<const f32x4*>(&hs_s[tid * 4]);
    f32x4 xv = LD4(x + (size_t)n * 1024 + tid * 4);
    f32x4 s = hv + xv;
    float sum = s[0] + s[1] + s[2] + s[3];
    float sq  = s[0]*s[0] + s[1]*s[1] + s[2]*s[2] + s[3]*s[3];
#pragma unroll
    for (int off = 32; off; off >>= 1) {
        sum += __shfl_down(sum, off);
        sq  += __shfl_down(sq, off);
    }
    const int wv = tid >> 6;
    if ((tid & 63) == 0) { red[wv] = sum; red[4 + wv] = sq; }
    __syncthreads();
    sum = red[0] + red[1] + red[2] + red[3];
    sq  = red[4] + red[5] + red[6] + red[7];
    float mu = sum * (1.f / 1024.f);
    float var = sq * (1.f / 1024.f) - mu * mu;
    float inv = rsqrtf(var + 1e-5f);
    ST4(h_out + (size_t)n * 1024 + tid * 4, (s - mu) * inv);
}

extern "C" void kernel_launch(void* const* d_in, const int* in_sizes, int n_in,
                              void* d_out, int out_size, void* d_ws, size_t ws_size,
                              hipStream_t stream) {
    const float* x      = (const float*)d_in[0];
    const float* c_in   = (const float*)d_in[1];
    const float* m_prev = (const float*)d_in[2];
    const float* n_prev = (const float*)d_in[3];
    const float* Wqkvo  = (const float*)d_in[4];
    const float* bqkvo  = (const float*)d_in[5];
    const float* Wuf    = (const float*)d_in[6];
    const float* buf    = (const float*)d_in[7];
    float* out = (float*)d_out;
    char* ws = (char*)d_ws;

    unsigned short* xb   = (unsigned short*)(ws);                         // 1 MB
    unsigned short* Wt   = (unsigned short*)(ws + (1u << 20));            // 8 MB
    unsigned short* qkvo = (unsigned short*)(ws + 9u * (1u << 20));       // 8 MB (2 bf16 halves)
    float* fe_ue         = (float*)(ws + 17u * (1u << 20));               // 32 KB

    prep_kernel<<<dim3(2048), dim3(256), 0, stream>>>(x, xb, Wqkvo, Wt, Wuf, buf, m_prev, fe_ue);
    gemm_qkvo  <<<dim3(1024), dim3(256), 0, stream>>>(xb, Wt, qkvo);
    stream_c   <<<dim3(4096), dim3(256), 0, stream>>>(c_in, qkvo, bqkvo, fe_ue, out);
    mid_kernel <<<dim3(512),  dim3(256), 0, stream>>>(qkvo, bqkvo, x, n_prev, fe_ue,
                                                      out + 67108864ull);
}

// Round 15
// 126.642 us; speedup vs baseline: 1.0675x; 1.0459x over previous
//
#include <hip/hip_runtime.h>
#include <hip/hip_bf16.h>
#include <math.h>

#define KSCALE 0.08838834764831845f  // 1/sqrt(128)

typedef __bf16 bf16x8 __attribute__((ext_vector_type(8)));
typedef float  f32x4  __attribute__((ext_vector_type(4)));
typedef unsigned short u16x4 __attribute__((ext_vector_type(4)));
typedef unsigned short u16x8 __attribute__((ext_vector_type(8)));

__device__ inline unsigned short f2bf(float f) {
    unsigned int u = __float_as_uint(f);
    unsigned int r = (u + 0x7FFFu + ((u >> 16) & 1u)) >> 16;
    return (unsigned short)r;
}
__device__ __forceinline__ float bf2f(unsigned short u) {
    return __uint_as_float(((unsigned int)u) << 16);
}
__device__ __forceinline__ f32x4 LD4(const float* p) {
    return *reinterpret_cast<const f32x4*>(p);
}
__device__ __forceinline__ f32x4 LD4H(const unsigned short* p) {
    u16x4 t = *reinterpret_cast<const u16x4*>(p);
    f32x4 r = { bf2f(t[0]), bf2f(t[1]), bf2f(t[2]), bf2f(t[3]) };
    return r;
}
__device__ __forceinline__ void ST4(float* p, f32x4 v) {
    *reinterpret_cast<f32x4*>(p) = v;
}

// async global->LDS, 16B per lane; lds dest must be wave-uniform base (+lane*16)
__device__ __forceinline__ void gll16(const unsigned short* g, unsigned short* l) {
    __builtin_amdgcn_global_load_lds(
        (const __attribute__((address_space(1))) unsigned int*)g,
        (__attribute__((address_space(3))) unsigned int*)l,
        16, 0, 0);
}

// ---- K0: prep: x->bf16 (0..511), W transpose 64x64 (512..1535), uf (1536..2047)
__global__ __launch_bounds__(256) void prep_kernel(const float* __restrict__ x,
                                                   unsigned short* __restrict__ xb,
                                                   const float* __restrict__ W,
                                                   unsigned short* __restrict__ Wt,
                                                   const float* __restrict__ Wuf,
                                                   const float* __restrict__ buf,
                                                   const float* __restrict__ m_prev,
                                                   float* __restrict__ fe_ue) {
    int b = blockIdx.x;
    const int tid = threadIdx.x;
    if (b < 512) {
        int t = b * 256 + tid;                    // 131072 float4s
        float4 v = reinterpret_cast<const float4*>(x)[t];
        u16x4 o = { f2bf(v.x), f2bf(v.y), f2bf(v.z), f2bf(v.w) };
        reinterpret_cast<u16x4*>(xb)[t] = o;
    } else if (b < 1536) {
        // transpose+convert: W [1024][4096] f32 -> Wt [4096][1024] bf16, 64x64 tiles
        __shared__ unsigned short tile[64][65];
        int bb = b - 512;                  // 0..1023
        int k0 = (bb & 15) * 64;           // 1024/64
        int n0 = (bb >> 4) * 64;           // 4096/64
        int r16 = tid >> 4, c4 = (tid & 15) * 4;
#pragma unroll
        for (int p = 0; p < 4; ++p) {
            int r = p * 16 + r16;
            float4 v = *reinterpret_cast<const float4*>(&W[(size_t)(k0 + r) * 4096 + n0 + c4]);
            tile[r][c4 + 0] = f2bf(v.x);
            tile[r][c4 + 1] = f2bf(v.y);
            tile[r][c4 + 2] = f2bf(v.z);
            tile[r][c4 + 3] = f2bf(v.w);
        }
        __syncthreads();
        int kc = (tid & 7) * 8, r32 = tid >> 3;
#pragma unroll
        for (int p = 0; p < 2; ++p) {
            int rr = p * 32 + r32;
            u16x8 o;
#pragma unroll
            for (int j = 0; j < 8; ++j) o[j] = tile[kc + j][rr];
            *reinterpret_cast<u16x8*>(&Wt[(size_t)(n0 + rr) * 1024 + k0 + kc]) = o;
        }
    } else {
        // u,f gates (f32 exact). wave w owns output cols 4w..4w+3
        const int n = b - 1536;
        const int lane = tid & 63, w = tid >> 6;
        const float* xr = x + (size_t)n * 1024;
        float4 p = {0.f, 0.f, 0.f, 0.f};
#pragma unroll
        for (int i = 0; i < 16; ++i) {
            int k = lane + i * 64;
            float xv = xr[k];
            float4 wv = *reinterpret_cast<const float4*>(&Wuf[(size_t)k * 16 + 4 * w]);
            p.x += xv * wv.x; p.y += xv * wv.y; p.z += xv * wv.z; p.w += xv * wv.w;
        }
#pragma unroll
        for (int off = 32; off; off >>= 1) {
            p.x += __shfl_down(p.x, off);
            p.y += __shfl_down(p.y, off);
            p.z += __shfl_down(p.z, off);
            p.w += __shfl_down(p.w, off);
        }
        if (lane == 0) {
#pragma unroll
            for (int t = 0; t < 2; ++t) {
                int h = 2 * w + t;
                float u = (t ? p.z : p.x) + buf[4 * w + 2 * t];
                float f = (t ? p.w : p.y) + buf[4 * w + 2 * t + 1];
                float mp = m_prev[h * 512 + n];
                float m = fmaxf(f + mp, u);
                fe_ue[(h * 512 + n) * 2 + 0] = expf(f + mp - m);
                fe_ue[(h * 512 + n) * 2 + 1] = expf(u - m);
            }
        }
    }
}

// ---- K1: split-K=2 GEMM, 64x64 tile, gll16 staging, 2-phase dbuf, bf16 out --
__global__ __launch_bounds__(256) void gemm_qkvo(const unsigned short* __restrict__ A,
                                                 const unsigned short* __restrict__ Bt,
                                                 unsigned short* __restrict__ Cp) {
    __shared__ __align__(16) unsigned short As[2][64 * 64];
    __shared__ __align__(16) unsigned short Bs[2][64 * 64];
    const int kh = blockIdx.x >> 9;
    const int t9 = blockIdx.x & 511;
    const int bn = t9 & 63;                 // 4096/64 N tiles
    const int bm = t9 >> 6;                 // 512/64 M tiles
    const int m0 = bm * 64, n0 = bn * 64;
    const size_t kb0 = (size_t)kh * 512;
    unsigned short* C = Cp + (size_t)kh * (512 * 4096);
    const int tid = threadIdx.x;
    const int lane = tid & 63, wave = tid >> 6;
    const int wr = wave >> 1, wc = wave & 1;     // 2x2 waves, each 32x32 out
    f32x4 acc[2][2] = {};

    const int srow = lane >> 3;          // row within 8-row chunk
    const int scol = (lane & 7) * 8;     // k element offset (16B granules)

#pragma unroll
    for (int c = 0; c < 2; ++c) {
        int chunk = wave * 2 + c;
        int row = chunk * 8 + srow;
        gll16(A + (size_t)(m0 + row) * 1024 + kb0 + scol, &As[0][chunk * 512]);
        gll16(Bt + (size_t)(n0 + row) * 1024 + kb0 + scol, &Bs[0][chunk * 512]);
    }
    __syncthreads();

    int cur = 0;
    for (int t = 0; t < 8; ++t) {
        if (t < 7) {
            size_t k0 = kb0 + (t + 1) * 64;
#pragma unroll
            for (int c = 0; c < 2; ++c) {
                int chunk = wave * 2 + c;
                int row = chunk * 8 + srow;
                gll16(A + (size_t)(m0 + row) * 1024 + k0 + scol, &As[cur ^ 1][chunk * 512]);
                gll16(Bt + (size_t)(n0 + row) * 1024 + k0 + scol, &Bs[cur ^ 1][chunk * 512]);
            }
        }
        const unsigned short* as = As[cur];
        const unsigned short* bs = Bs[cur];
        const int row = lane & 15;
        const int kof = (lane >> 4) * 8;
#pragma unroll
        for (int kk = 0; kk < 2; ++kk) {
            int kb = kk * 32 + kof;
            bf16x8 a0 = *reinterpret_cast<const bf16x8*>(&as[(wr * 32 + row) * 64 + kb]);
            bf16x8 a1 = *reinterpret_cast<const bf16x8*>(&as[(wr * 32 + 16 + row) * 64 + kb]);
            bf16x8 b0 = *reinterpret_cast<const bf16x8*>(&bs[(wc * 32 + row) * 64 + kb]);
            bf16x8 b1 = *reinterpret_cast<const bf16x8*>(&bs[(wc * 32 + 16 + row) * 64 + kb]);
            acc[0][0] = __builtin_amdgcn_mfma_f32_16x16x32_bf16(a0, b0, acc[0][0], 0, 0, 0);
            acc[0][1] = __builtin_amdgcn_mfma_f32_16x16x32_bf16(a0, b1, acc[0][1], 0, 0, 0);
            acc[1][0] = __builtin_amdgcn_mfma_f32_16x16x32_bf16(a1, b0, acc[1][0], 0, 0, 0);
            acc[1][1] = __builtin_amdgcn_mfma_f32_16x16x32_bf16(a1, b1, acc[1][1], 0, 0, 0);
        }
        __syncthreads();
        cur ^= 1;
    }

    // epilogue: acc -> bf16 -> LDS (reuse As, now dead) -> coalesced global
    unsigned short* cs = &As[0][0];          // [64][64] ushort = 8 KB
    const int cn = lane & 15, cm = (lane >> 4) * 4;
#pragma unroll
    for (int i = 0; i < 2; ++i)
#pragma unroll
        for (int j = 0; j < 2; ++j) {
            int r0 = wr * 32 + i * 16 + cm;
            int c0 = wc * 32 + j * 16 + cn;
#pragma unroll
            for (int v = 0; v < 4; ++v)
                cs[(r0 + v) * 64 + c0] = f2bf(acc[i][j][v]);
        }
    __syncthreads();
    {
        int row = tid >> 2, seg = tid & 3;   // 64 rows x 4 segs of 16 ushort
        const u16x8* src = reinterpret_cast<const u16x8*>(&cs[row * 64 + seg * 16]);
        u16x8* dst = reinterpret_cast<u16x8*>(&C[(size_t)(m0 + row) * 4096 + n0 + seg * 16]);
        dst[0] = src[0];
        dst[1] = src[1];
    }
}

// ---- K2: mid: per-token (512 blocks). 32-lane group g handles head g.
// Sums bf16 split-K halves + bias, gates/reductions, emits uvk (ue*v || k),
// residual+LayerNorm inline.
__global__ __launch_bounds__(256) void mid_kernel(const unsigned short* __restrict__ qkvo,
                                                  const float* __restrict__ bias,
                                                  const float* __restrict__ x,
                                                  const float* __restrict__ n_prev,
                                                  const float* __restrict__ fe_ue,
                                                  float* __restrict__ uvk,
                                                  float* __restrict__ fe_arr,
                                                  float* __restrict__ h_out) {
    const int n = blockIdx.x;
    const int tid = threadIdx.x;
    const int g = tid >> 5, l = tid & 31;     // head group, lane-in-group
    __shared__ float hs_s[1024];
    __shared__ float red[8];

    const unsigned short* bA = qkvo + (size_t)n * 4096 + g * 512;
    const unsigned short* bB = bA + (size_t)512 * 4096;
    const float* bs = bias + g * 512;
    const int d4 = l * 4;
    const int hn = g * 512 + n;

    f32x4 q = LD4H(bA + d4)       + LD4H(bB + d4)       + LD4(bs + d4);
    f32x4 k = (LD4H(bA + 128 + d4) + LD4H(bB + 128 + d4) + LD4(bs + 128 + d4)) * KSCALE;
    f32x4 v = LD4H(bA + 256 + d4) + LD4H(bB + 256 + d4) + LD4(bs + 256 + d4);
    f32x4 o = LD4H(bA + 384 + d4) + LD4H(bB + 384 + d4) + LD4(bs + 384 + d4);
    const float fe = fe_ue[hn * 2 + 0];
    const float ue = fe_ue[hn * 2 + 1];
    f32x4 np = LD4(n_prev + (size_t)hn * 128 + d4);
    f32x4 nn = fe * np + ue * k;

    float kq = q[0]*k[0] + q[1]*k[1] + q[2]*k[2] + q[3]*k[3];
    float nq = q[0]*nn[0] + q[1]*nn[1] + q[2]*nn[2] + q[3]*nn[3];
#pragma unroll
    for (int off = 16; off; off >>= 1) {
        kq += __shfl_down(kq, off, 32);
        nq += __shfl_down(nq, off, 32);
    }
    kq = __shfl(kq, 0, 32);
    nq = __shfl(nq, 0, 32);
    const float gs = kq / fmaxf(fabsf(nq), 1.0f);

    ST4(uvk + (size_t)hn * 256 + d4, ue * v);
    ST4(uvk + (size_t)hn * 256 + 128 + d4, k);
    if (l == 0) fe_arr[hn] = fe;

#pragma unroll
    for (int j = 0; j < 4; ++j)
        hs_s[g * 128 + d4 + j] = v[j] * gs / (1.f + expf(-o[j]));
    __syncthreads();

    // residual + LayerNorm over 1024
    f32x4 hv = *reinterpret_cast<const f32x4*>(&hs_s[tid * 4]);
    f32x4 xv = LD4(x + (size_t)n * 1024 + tid * 4);
    f32x4 s = hv + xv;
    float sum = s[0] + s[1] + s[2] + s[3];
    float sq  = s[0]*s[0] + s[1]*s[1] + s[2]*s[2] + s[3]*s[3];
#pragma unroll
    for (int off = 32; off; off >>= 1) {
        sum += __shfl_down(sum, off);
        sq  += __shfl_down(sq, off);
    }
    const int wv = tid >> 6;
    if ((tid & 63) == 0) { red[wv] = sum; red[4 + wv] = sq; }
    __syncthreads();
    sum = red[0] + red[1] + red[2] + red[3];
    sq  = red[4] + red[5] + red[6] + red[7];
    float mu = sum * (1.f / 1024.f);
    float var = sq * (1.f / 1024.f) - mu * mu;
    float inv = rsqrtf(var + 1e-5f);
    ST4(h_out + (size_t)n * 1024 + tid * 4, (s - mu) * inv);
}

// ---- K3: pure c stream (NT, 4096 blocks, 1 hn/block) ------------------------
__global__ __launch_bounds__(256) void stream_c(const float* __restrict__ c_in,
                                                const float* __restrict__ uvk,
                                                const float* __restrict__ fe_arr,
                                                float* __restrict__ c_out) {
    const int hn = blockIdx.x;              // h*512 + n
    const int tid = threadIdx.x;
    __shared__ __align__(16) float kv_s[256];
    if (tid < 64)
        *reinterpret_cast<f32x4*>(&kv_s[tid * 4]) = LD4(uvk + (size_t)hn * 256 + tid * 4);
    const float fe = fe_arr[hn];
    __syncthreads();

    const int j4 = (tid & 31) * 4;
    const f32x4 kk = *reinterpret_cast<const f32x4*>(&kv_s[128 + j4]);
    const int i0 = tid >> 5;

    const f32x4* cin4 = reinterpret_cast<const f32x4*>(c_in + (size_t)hn * 16384);
    f32x4* cout4 = reinterpret_cast<f32x4*>(c_out + (size_t)hn * 16384);
#pragma unroll
    for (int it = 0; it < 16; ++it) {
        int e4 = tid + it * 256;
        float uvi = kv_s[i0 + it * 8];      // broadcast within 32-lane group
        f32x4 cv = __builtin_nontemporal_load(&cin4[e4]);
        f32x4 ov = fe * cv + uvi * kk;
        __builtin_nontemporal_store(ov, &cout4[e4]);
    }
}

extern "C" void kernel_launch(void* const* d_in, const int* in_sizes, int n_in,
                              void* d_out, int out_size, void* d_ws, size_t ws_size,
                              hipStream_t stream) {
    const float* x      = (const float*)d_in[0];
    const float* c_in   = (const float*)d_in[1];
    const float* m_prev = (const float*)d_in[2];
    const float* n_prev = (const float*)d_in[3];
    const float* Wqkvo  = (const float*)d_in[4];
    const float* bqkvo  = (const float*)d_in[5];
    const float* Wuf    = (const float*)d_in[6];
    const float* buf    = (const float*)d_in[7];
    float* out = (float*)d_out;
    char* ws = (char*)d_ws;

    unsigned short* xb   = (unsigned short*)(ws);                         // 1 MB
    unsigned short* Wt   = (unsigned short*)(ws + (1u << 20));            // 8 MB
    unsigned short* qkvo = (unsigned short*)(ws + 9u * (1u << 20));       // 8 MB (2 bf16 halves)
    float* fe_ue         = (float*)(ws + 17u * (1u << 20));               // 32 KB
    float* fe_arr        = (float*)(ws + 17u * (1u << 20) + (1u << 16));  // 16 KB
    float* uvk           = (float*)(ws + 18u * (1u << 20));               // 4 MB

    prep_kernel<<<dim3(2048), dim3(256), 0, stream>>>(x, xb, Wqkvo, Wt, Wuf, buf, m_prev, fe_ue);
    gemm_qkvo  <<<dim3(1024), dim3(256), 0, stream>>>(xb, Wt, qkvo);
    mid_kernel <<<dim3(512),  dim3(256), 0, stream>>>(qkvo, bqkvo, x, n_prev, fe_ue,
                                                      uvk, fe_arr, out + 67108864ull);
    stream_c   <<<dim3(4096), dim3(256), 0, stream>>>(c_in, uvk, fe_arr, out);
}